// Round 4
// baseline (9263.660 us; speedup 1.0000x reference)
//
#include <hip/hip_runtime.h>
#include <math.h>

#define NEG_INF (-__builtin_inff())
#define POS_INF (__builtin_inff())

// ===================== DPP int max (valid f32 max for x >= 0) =====================
__device__ __forceinline__ int imax_i(int a, int b) { return a > b ? a : b; }

template<int CTRL, int RMASK>
__device__ __forceinline__ int dpp_imax_step(int y) {
  const int t = __builtin_amdgcn_update_dpp(y, y, CTRL, RMASK, 0xf, false);
  return imax_i(y, t);
}

// ============================ FPS (pruned, exact) ============================
// Bit-exact replica of reference lax.scan FPS (see R1-R3 notes).
// MODE 0: real. MODE 1: force-skip after it0 (floor ablation, scratch out).
// MODE 2: never skip (compute-ceiling ablation, scratch out).
// Reduce: per-wave int-DPP max on f32 bits (cval>=0), uniform tie-resolve via
// ballot; block combine via one LDS u64 atomicMax slot (4-deep rotation).
template<int N, int PPT, int S, int NT, int MODE>
__global__ __launch_bounds__(NT) void fpsp_kernel(const float* __restrict__ pos,
                                                  float* __restrict__ q_out)
{
  constexpr int CELLS = 4096;      // 16^3 Morton cells
  constexpr int CPT = CELLS / NT;
  static_assert(N == NT * PPT, "chunking");
  static_assert(S <= CELLS, "winner list fits in hist");

  const int b = blockIdx.x;
  const int t = threadIdx.x;
  pos += (size_t)b * N * 3;
  q_out += (size_t)b * S * 3;

  __shared__ float sx[N], sy[N], sz[N];      // ORIGINAL-index order
  __shared__ int sorder[N];                  // slot -> orig
  __shared__ int hist[CELLS];                // reused as winner list after setup
  __shared__ int scanbuf[NT];
  __shared__ unsigned long long slot[4];     // rotating combine slots

  int* const swin = hist;                    // alias: setup-only vs loop-only

  // ---- load coords + cell histogram ----
  for (int i = t; i < CELLS; i += NT) hist[i] = 0;
  if (t < 4) slot[t] = 0;
  __syncthreads();
  for (int i = t; i < N; i += NT) {
    const float x = pos[3*i+0], y = pos[3*i+1], z = pos[3*i+2];
    sx[i] = x; sy[i] = y; sz[i] = z;
    int cx = (int)(x * 16.f); cx = cx < 0 ? 0 : (cx > 15 ? 15 : cx);
    int cy = (int)(y * 16.f); cy = cy < 0 ? 0 : (cy > 15 ? 15 : cy);
    int cz = (int)(z * 16.f); cz = cz < 0 ? 0 : (cz > 15 ? 15 : cz);
    int m = 0;
#pragma unroll
    for (int k = 0; k < 4; ++k)
      m |= (((cx >> k) & 1) << (3*k+2)) | (((cy >> k) & 1) << (3*k+1)) | (((cz >> k) & 1) << (3*k));
    atomicAdd(&hist[m], 1);
  }
  __syncthreads();
  // ---- exclusive scan of hist ----
  int loc[CPT]; int run = 0;
#pragma unroll
  for (int j = 0; j < CPT; ++j) { loc[j] = run; run += hist[t*CPT + j]; }
  scanbuf[t] = run;
  __syncthreads();
  for (int off = 1; off < NT; off <<= 1) {
    const int o = (t >= off) ? scanbuf[t - off] : 0;
    __syncthreads();
    scanbuf[t] += o;
    __syncthreads();
  }
  const int base = scanbuf[t] - run;   // exclusive block offset
#pragma unroll
  for (int j = 0; j < CPT; ++j) hist[t*CPT + j] = base + loc[j];
  __syncthreads();
  // ---- scatter (slot -> orig) ----
  for (int i = t; i < N; i += NT) {
    const float x = sx[i], y = sy[i], z = sz[i];
    int cx = (int)(x * 16.f); cx = cx < 0 ? 0 : (cx > 15 ? 15 : cx);
    int cy = (int)(y * 16.f); cy = cy < 0 ? 0 : (cy > 15 ? 15 : cy);
    int cz = (int)(z * 16.f); cz = cz < 0 ? 0 : (cz > 15 ? 15 : cz);
    int m = 0;
#pragma unroll
    for (int k = 0; k < 4; ++k)
      m |= (((cx >> k) & 1) << (3*k+2)) | (((cy >> k) & 1) << (3*k+1)) | (((cz >> k) & 1) << (3*k));
    const int sl = atomicAdd(&hist[m], 1);
    sorder[sl] = i;
  }
  __syncthreads();
  // ---- gather chunk into registers + bbox ----
  float px[PPT], py[PPT], pz[PPT], d[PPT];
  int og[PPT];
  float bxmin = POS_INF, bxmax = NEG_INF, bymin = POS_INF, bymax = NEG_INF,
        bzmin = POS_INF, bzmax = NEG_INF;
#pragma unroll
  for (int j = 0; j < PPT; ++j) {
    const int o = sorder[t*PPT + j];
    og[j] = o;
    const float x = sx[o], y = sy[o], z = sz[o];
    px[j] = x; py[j] = y; pz[j] = z;
    bxmin = fminf(bxmin, x); bxmax = fmaxf(bxmax, x);
    bymin = fminf(bymin, y); bymax = fmaxf(bymax, y);
    bzmin = fminf(bzmin, z); bzmax = fmaxf(bzmax, z);
    d[j] = POS_INF;
  }
  __syncthreads();   // hist fully consumed (sorder reads done) before swin reuse

  float cval = POS_INF;      // cached chunk max (inf -> force first recompute)
  int corig = 0x7fffffff;    // cached arg (orig idx)

  int worig = 0;             // first selected point = index 0
  int p = 0;

  for (int it = 0; it < S; ++it) {
    if (t == 0) swin[it] = worig;
    const float lx = sx[worig], ly = sy[worig], lz = sz[worig];

    // conservative bbox min dist^2 to (lx,ly,lz)
    const float ddx = fmaxf(0.f, fmaxf(bxmin - lx, lx - bxmax));
    const float ddy = fmaxf(0.f, fmaxf(bymin - ly, ly - bymax));
    const float ddz = fmaxf(0.f, fmaxf(bzmin - lz, lz - bzmax));
    const float mind2 = ddx*ddx + ddy*ddy + ddz*ddz;

    bool rec;
    if (MODE == 1)      rec = (it == 0);
    else if (MODE == 2) rec = true;
    else                rec = !(mind2 * 0.99999f >= cval);

    if (rec) {
      float bv = -1.f; int bo = 0x7fffffff;
#pragma unroll
      for (int j = 0; j < PPT; ++j) {
        const float dx = __fsub_rn(px[j], lx);
        const float dy = __fsub_rn(py[j], ly);
        const float dz = __fsub_rn(pz[j], lz);
        const float nd = __fadd_rn(__fadd_rn(__fmul_rn(dx, dx), __fmul_rn(dy, dy)),
                                   __fmul_rn(dz, dz));
        const float dn = __builtin_fminf(d[j], nd);
        d[j] = dn;
        if (dn > bv || (dn == bv && og[j] < bo)) { bv = dn; bo = og[j]; }
      }
      cval = bv; corig = bo;
    }

    // MODE 1: keep the serial dependence worig->coords->bbox->reduce alive
    // (fma(mind2,1e30,1e30) >= 1e30 > any real cval, so fminf returns cval).
    float cvx = cval;
    if (MODE == 1) cvx = fminf(cval, __fmaf_rn(mind2, 1e30f, 1e30f));

    // ---- wave64 int-DPP max on f32 bits (cvx >= 0); result lands in lane 63 ----
    const int x = __float_as_int(cvx);
    int y = x;
    y = dpp_imax_step<0x111, 0xf>(y);  // row_shr:1
    y = dpp_imax_step<0x112, 0xf>(y);  // row_shr:2
    y = dpp_imax_step<0x114, 0xf>(y);  // row_shr:4
    y = dpp_imax_step<0x118, 0xf>(y);  // row_shr:8
    y = dpp_imax_step<0x142, 0xa>(y);  // row_bcast:15 -> rows 1,3
    y = dpp_imax_step<0x143, 0xc>(y);  // row_bcast:31 -> rows 2,3
    const int mvb = __builtin_amdgcn_readlane(y, 63);
    unsigned long long tie = __ballot(x == mvb);
    int wo = 0x7fffffff;
    while (tie) {                      // usually a single iteration
      const int l = __builtin_ctzll(tie);
      const int o = __builtin_amdgcn_readlane(corig, l);
      wo = wo < o ? wo : o;
      tie &= tie - 1;
    }
    // one atomic per wave into the rotating combine slot
    if ((t & 63) == 0)
      atomicMax(&slot[p], ((unsigned long long)(unsigned)mvb << 32) |
                          (unsigned)~(unsigned)wo);
    if (t == 0) slot[(p + 1) & 3] = 0;   // reset two-ahead-safe (distinct slot)
    __syncthreads();
    const unsigned long long wm = slot[p];
    worig = (int)(~(unsigned)(wm & 0xffffffffULL));
    p = (p + 1) & 3;
  }

  __syncthreads();   // swin[] complete before coalesced writeback
  for (int s = t; s < S; s += NT) {
    const int o = swin[s];
    q_out[3*s+0] = sx[o]; q_out[3*s+1] = sy[o]; q_out[3*s+2] = sz[o];
  }
}

// ============================ radius-KNN ============================
#define KNN_CAP 2048

__global__ __launch_bounds__(256) void knn_kernel(const float* __restrict__ cand,
                                                  const float* __restrict__ qpos,
                                                  int nq_per_graph, int n_cand, float r2,
                                                  int* __restrict__ nbr_out,
                                                  int* __restrict__ cnt_out)
{
  const int qi = blockIdx.x;
  const int t = threadIdx.x;
  const int b = qi / nq_per_graph;
  const float* cb = cand + (size_t)b * n_cand * 3;
  const float qx = qpos[3*qi+0], qy = qpos[3*qi+1], qz = qpos[3*qi+2];

  __shared__ unsigned long long keys[KNN_CAP];
  __shared__ int s_cnt;
  if (t == 0) s_cnt = 0;
  __syncthreads();

  for (int i = t; i < n_cand; i += 256) {
    const float dx = __fsub_rn(cb[3*i+0], qx);
    const float dy = __fsub_rn(cb[3*i+1], qy);
    const float dz = __fsub_rn(cb[3*i+2], qz);
    const float d2 = __fadd_rn(__fadd_rn(__fmul_rn(dx, dx), __fmul_rn(dy, dy)),
                               __fmul_rn(dz, dz));
    if (d2 <= r2) {
      const int p = atomicAdd(&s_cnt, 1);
      if (p < KNN_CAP) keys[p] = ((unsigned long long)__float_as_uint(d2) << 32) | (unsigned)i;
    }
  }
  __syncthreads();
  const int M = min(s_cnt, KNN_CAP);
  const int out_n = min(M, 64);
  if (M > 64) {
    int P = 128; while (P < M) P <<= 1;
    for (int i = M + t; i < P; i += 256) keys[i] = ~0ULL;
    __syncthreads();
    for (int k = 2; k <= P; k <<= 1) {
      for (int j = k >> 1; j > 0; j >>= 1) {
        for (int i = t; i < P; i += 256) {
          const int l = i ^ j;
          if (l > i) {
            const unsigned long long a = keys[i], c = keys[l];
            const bool up = ((i & k) == 0);
            if ((a > c) == up) { keys[i] = c; keys[l] = a; }
          }
        }
        __syncthreads();
      }
    }
  }
  if (t < 64) nbr_out[(size_t)qi*64 + t] = (t < out_n) ? (int)(keys[t] & 0xffffffffu) : -1;
  if (t == 0) cnt_out[qi] = out_n;
}

// ============================ SA1 edge MLP (3->64->64->128) + max ============================
__global__ __launch_bounds__(256) void mlp1_kernel(const float* __restrict__ pos,
                                                   const float* __restrict__ q1,
                                                   const int* __restrict__ nbr,
                                                   const int* __restrict__ cnt_,
                                                   const float* __restrict__ W1, const float* __restrict__ b1,
                                                   const float* __restrict__ W2, const float* __restrict__ b2,
                                                   const float* __restrict__ W3, const float* __restrict__ b3,
                                                   float* __restrict__ x1)
{
  const int qi = blockIdx.x;
  const int t = threadIdx.x;
  const int bg = qi >> 12;                       // 4096 queries per graph
  const float* cb = pos + (size_t)bg * 8192 * 3;

  __shared__ float sW1[3*64];
  __shared__ float sb1[64];
  __shared__ float sW2[64*64];
  __shared__ float sb2[64];
  __shared__ float sW3[64*128];
  __shared__ float sb3[128];
  __shared__ float featT[3][64];                 // k-major rel
  __shared__ float h1[64][65];
  __shared__ float h2b[64][65];

  const int cnt = cnt_[qi];
  const float qx = q1[3*qi+0], qy = q1[3*qi+1], qz = q1[3*qi+2];

  if (t < 64) {
    float r0 = 0.f, r1 = 0.f, r2v = 0.f;
    if (t < cnt) {
      const int nb = nbr[(size_t)qi*64 + t];
      r0 = cb[3*nb+0] - qx;
      r1 = cb[3*nb+1] - qy;
      r2v = cb[3*nb+2] - qz;
    }
    featT[0][t] = r0; featT[1][t] = r1; featT[2][t] = r2v;
  }
  for (int i = t; i < 192; i += 256) sW1[i] = W1[i];
  if (t < 64) { sb1[t] = b1[t]; sb2[t] = b2[t]; }
  for (int i = t; i < 4096; i += 256) sW2[i] = W2[i];
  for (int i = t; i < 8192; i += 256) sW3[i] = W3[i];
  if (t < 128) sb3[t] = b3[t];
  __syncthreads();

  const int e = t & 63, cg = t >> 6;
  { // layer1: 16 channels per thread
    const int c0 = cg * 16;
    const float a0 = featT[0][e], a1 = featT[1][e], a2 = featT[2][e];
#pragma unroll
    for (int i = 0; i < 16; ++i) {
      float v = sb1[c0+i];
      v = fmaf(a0, sW1[0*64 + c0+i], v);
      v = fmaf(a1, sW1[1*64 + c0+i], v);
      v = fmaf(a2, sW1[2*64 + c0+i], v);
      h1[e][c0+i] = fmaxf(v, 0.f);
    }
  }
  __syncthreads();
  { // layer2
    const int c0 = cg * 16;
    float acc[16];
#pragma unroll
    for (int i = 0; i < 16; ++i) acc[i] = sb2[c0+i];
    for (int k = 0; k < 64; ++k) {
      const float a = h1[e][k];
      const float4* wp = reinterpret_cast<const float4*>(&sW2[k*64 + c0]);
#pragma unroll
      for (int i = 0; i < 4; ++i) {
        const float4 w = wp[i];
        acc[4*i+0] = fmaf(a, w.x, acc[4*i+0]);
        acc[4*i+1] = fmaf(a, w.y, acc[4*i+1]);
        acc[4*i+2] = fmaf(a, w.z, acc[4*i+2]);
        acc[4*i+3] = fmaf(a, w.w, acc[4*i+3]);
      }
    }
#pragma unroll
    for (int i = 0; i < 16; ++i) h2b[e][c0+i] = fmaxf(acc[i], 0.f);
  }
  __syncthreads();
  float acc3[32];
  const int c0h = cg * 32;
  { // layer3 (no relu)
#pragma unroll
    for (int i = 0; i < 32; ++i) acc3[i] = sb3[c0h+i];
    for (int k = 0; k < 64; ++k) {
      const float a = h2b[e][k];
      const float4* wp = reinterpret_cast<const float4*>(&sW3[k*128 + c0h]);
#pragma unroll
      for (int i = 0; i < 8; ++i) {
        const float4 w = wp[i];
        acc3[4*i+0] = fmaf(a, w.x, acc3[4*i+0]);
        acc3[4*i+1] = fmaf(a, w.y, acc3[4*i+1]);
        acc3[4*i+2] = fmaf(a, w.z, acc3[4*i+2]);
        acc3[4*i+3] = fmaf(a, w.w, acc3[4*i+3]);
      }
    }
  }
  __syncthreads();       // all reads of h1/h2b done before re-staging
  {
    const bool valid = (e < cnt);
#pragma unroll
    for (int i = 0; i < 32; ++i) {
      const float v = valid ? acc3[i] : NEG_INF;
      const int c = c0h + i;
      if (c < 64) h1[e][c] = v; else h2b[e][c-64] = v;
    }
  }
  __syncthreads();
  if (t < 128) {
    float m = NEG_INF;
    if (t < 64) {
      for (int ee = 0; ee < 64; ++ee) m = fmaxf(m, h1[ee][t]);
    } else {
      for (int ee = 0; ee < 64; ++ee) m = fmaxf(m, h2b[ee][t-64]);
    }
    x1[(size_t)qi*128 + t] = m;
  }
}

// ============================ SA2 edge MLP (131->128->128->256) + max ============================
__global__ __launch_bounds__(256) void mlp2_kernel(const float* __restrict__ q1,
                                                   const float* __restrict__ x1,
                                                   const float* __restrict__ q2,
                                                   const int* __restrict__ nbr,
                                                   const int* __restrict__ cnt_,
                                                   const float* __restrict__ W1, const float* __restrict__ b1,
                                                   const float* __restrict__ W2, const float* __restrict__ b2,
                                                   const float* __restrict__ W3, const float* __restrict__ b3,
                                                   float* __restrict__ x2)
{
  const int qi = blockIdx.x;
  const int t = threadIdx.x;
  const int bg = qi >> 10;                       // 1024 queries per graph
  const float* cb = q1 + (size_t)bg * 4096 * 3;
  const float* xb = x1 + (size_t)bg * 4096 * 128;

  __shared__ float sW[131*128];                  // staged layer weights
  __shared__ float sb[256];
  __shared__ float featT[131][64];               // k-major feat; reused as h2
  __shared__ float hbuf[64][129];                // h1; reused as h3 stage
  __shared__ int snb[64];

  const int cnt = cnt_[qi];
  const float qx = q2[3*qi+0], qy = q2[3*qi+1], qz = q2[3*qi+2];

  if (t < 64) {
    const int nb = (t < cnt) ? nbr[(size_t)qi*64 + t] : 0;
    snb[t] = nb;
    float r0 = 0.f, r1 = 0.f, r2v = 0.f;
    if (t < cnt) {
      r0 = cb[3*nb+0] - qx;
      r1 = cb[3*nb+1] - qy;
      r2v = cb[3*nb+2] - qz;
    }
    featT[128][t] = r0; featT[129][t] = r1; featT[130][t] = r2v;
  }
  for (int i = t; i < 131*128; i += 256) sW[i] = W1[i];
  if (t < 128) sb[t] = b1[t];
  __syncthreads();
  for (int idx = t; idx < 64*128; idx += 256) {   // gather x1 features
    const int e = idx >> 7, k = idx & 127;
    featT[k][e] = (e < cnt) ? xb[(size_t)snb[e]*128 + k] : 0.f;
  }
  __syncthreads();

  const int e = t & 63, cg = t >> 6, c0 = cg * 32;
  float acc[32];
  { // layer1: 131 -> 128
#pragma unroll
    for (int i = 0; i < 32; ++i) acc[i] = sb[c0+i];
    for (int k = 0; k < 131; ++k) {
      const float a = featT[k][e];
      const float4* wp = reinterpret_cast<const float4*>(&sW[k*128 + c0]);
#pragma unroll
      for (int i = 0; i < 8; ++i) {
        const float4 w = wp[i];
        acc[4*i+0] = fmaf(a, w.x, acc[4*i+0]);
        acc[4*i+1] = fmaf(a, w.y, acc[4*i+1]);
        acc[4*i+2] = fmaf(a, w.z, acc[4*i+2]);
        acc[4*i+3] = fmaf(a, w.w, acc[4*i+3]);
      }
    }
#pragma unroll
    for (int i = 0; i < 32; ++i) hbuf[e][c0+i] = fmaxf(acc[i], 0.f);
  }
  __syncthreads();
  for (int i = t; i < 128*128; i += 256) sW[i] = W2[i];
  if (t < 128) sb[t] = b2[t];
  __syncthreads();
  { // layer2: 128 -> 128 ; h2 stored k-major into featT region
#pragma unroll
    for (int i = 0; i < 32; ++i) acc[i] = sb[c0+i];
    for (int k = 0; k < 128; ++k) {
      const float a = hbuf[e][k];
      const float4* wp = reinterpret_cast<const float4*>(&sW[k*128 + c0]);
#pragma unroll
      for (int i = 0; i < 8; ++i) {
        const float4 w = wp[i];
        acc[4*i+0] = fmaf(a, w.x, acc[4*i+0]);
        acc[4*i+1] = fmaf(a, w.y, acc[4*i+1]);
        acc[4*i+2] = fmaf(a, w.z, acc[4*i+2]);
        acc[4*i+3] = fmaf(a, w.w, acc[4*i+3]);
      }
    }
  }
  __syncthreads();   // everyone done reading hbuf(h1) and sW(W2)
#pragma unroll
  for (int i = 0; i < 32; ++i) featT[c0+i][e] = fmaxf(acc[i], 0.f);
  __syncthreads();
  // layer3: 128 -> 256, in two column halves (staged W3 halves), masked max
  for (int hh = 0; hh < 2; ++hh) {
    for (int i = t; i < 128*128; i += 256) {
      const int k = i >> 7, c = i & 127;
      sW[i] = W3[k*256 + hh*128 + c];
    }
    if (t < 128) sb[t] = b3[hh*128 + t];
    __syncthreads();
#pragma unroll
    for (int i = 0; i < 32; ++i) acc[i] = sb[c0+i];
    for (int k = 0; k < 128; ++k) {
      const float a = featT[k][e];
      const float4* wp = reinterpret_cast<const float4*>(&sW[k*128 + c0]);
#pragma unroll
      for (int i = 0; i < 8; ++i) {
        const float4 w = wp[i];
        acc[4*i+0] = fmaf(a, w.x, acc[4*i+0]);
        acc[4*i+1] = fmaf(a, w.y, acc[4*i+1]);
        acc[4*i+2] = fmaf(a, w.z, acc[4*i+2]);
        acc[4*i+3] = fmaf(a, w.w, acc[4*i+3]);
      }
    }
    const bool valid = (e < cnt);
#pragma unroll
    for (int i = 0; i < 32; ++i) hbuf[e][c0+i] = valid ? acc[i] : NEG_INF;
    __syncthreads();
    if (t < 128) {
      float m = NEG_INF;
      for (int ee = 0; ee < 64; ++ee) m = fmaxf(m, hbuf[ee][t]);
      x2[(size_t)qi*256 + hh*128 + t] = m;
    }
    __syncthreads();  // hbuf reads + sW reads done before next half
  }
}

// ============================ head MLP (256->256->128->1, sigmoid) ============================
__global__ __launch_bounds__(256) void head_kernel(const float* __restrict__ x2,
                                                   const float* __restrict__ W1, const float* __restrict__ b1,
                                                   const float* __restrict__ W2, const float* __restrict__ b2,
                                                   const float* __restrict__ W3, const float* __restrict__ b3,
                                                   float* __restrict__ out)
{
  const int pt = blockIdx.x;
  const int t = threadIdx.x;
  __shared__ float sx[256];
  __shared__ float sh1[256];
  __shared__ float sh2[128];
  __shared__ float red[128];

  sx[t] = x2[(size_t)pt*256 + t];
  __syncthreads();
  float a1 = b1[t];
  for (int k = 0; k < 256; ++k) a1 = fmaf(sx[k], W1[k*256 + t], a1);
  sh1[t] = fmaxf(a1, 0.f);
  __syncthreads();
  if (t < 128) {
    float a2 = b2[t];
    for (int k = 0; k < 256; ++k) a2 = fmaf(sh1[k], W2[k*128 + t], a2);
    sh2[t] = fmaxf(a2, 0.f);
  }
  __syncthreads();
  if (t < 128) red[t] = sh2[t] * W3[t];
  __syncthreads();
  for (int o = 64; o > 0; o >>= 1) {
    if (t < o) red[t] += red[t + o];
    __syncthreads();
  }
  if (t == 0) {
    const float v = red[0] + b3[0];
    out[pt] = 1.f / (1.f + expf(-v));
  }
}

// ============================ launcher ============================
extern "C" void kernel_launch(void* const* d_in, const int* in_sizes, int n_in,
                              void* d_out, int out_size, void* d_ws, size_t ws_size,
                              hipStream_t stream)
{
  (void)in_sizes; (void)n_in; (void)out_size; (void)ws_size;
  const float* pos  = (const float*)d_in[0];
  // d_in[1] = batch (sorted, equal graphs) — layout implied, unused
  const float* s1W1 = (const float*)d_in[2];  const float* s1b1 = (const float*)d_in[3];
  const float* s1W2 = (const float*)d_in[4];  const float* s1b2 = (const float*)d_in[5];
  const float* s1W3 = (const float*)d_in[6];  const float* s1b3 = (const float*)d_in[7];
  const float* s2W1 = (const float*)d_in[8];  const float* s2b1 = (const float*)d_in[9];
  const float* s2W2 = (const float*)d_in[10]; const float* s2b2 = (const float*)d_in[11];
  const float* s2W3 = (const float*)d_in[12]; const float* s2b3 = (const float*)d_in[13];
  const float* l1W  = (const float*)d_in[14]; const float* l1b  = (const float*)d_in[15];
  const float* l2W  = (const float*)d_in[16]; const float* l2b  = (const float*)d_in[17];
  const float* l3W  = (const float*)d_in[18]; const float* l3b  = (const float*)d_in[19];
  float* out = (float*)d_out;

  char* w = (char*)d_ws;
  size_t off = 0;
  auto alloc = [&](size_t bytes) -> void* {
    void* p = w + off;
    off += (bytes + 255) & ~(size_t)255;
    return p;
  };
  float* q1   = (float*)alloc((size_t)2*4096*3*4);
  float* q2   = (float*)alloc((size_t)2*1024*3*4);
  float* x1   = (float*)alloc((size_t)8192*128*4);
  float* x2   = (float*)alloc((size_t)2048*256*4);
  int*   nbr1 = (int*)alloc((size_t)8192*64*4);
  int*   cnt1 = (int*)alloc((size_t)8192*4);
  int*   nbr2 = (int*)alloc((size_t)2048*64*4);
  int*   cnt2 = (int*)alloc((size_t)2048*4);
  float* qabl = (float*)alloc((size_t)2*4096*3*4);   // ablation scratch output

  const float R1SQ = (float)(0.2 * 0.2);   // mirrors Python double math -> f32
  const float R2SQ = (float)(0.4 * 0.4);

  // ---- real pipeline (MODE 0, 1024 threads) ----
  fpsp_kernel<8192, 8, 4096, 1024, 0><<<dim3(2), dim3(1024), 0, stream>>>(pos, q1);
  knn_kernel<<<dim3(8192), dim3(256), 0, stream>>>(pos, q1, 4096, 8192, R1SQ, nbr1, cnt1);
  mlp1_kernel<<<dim3(8192), dim3(256), 0, stream>>>(pos, q1, nbr1, cnt1,
                                                    s1W1, s1b1, s1W2, s1b2, s1W3, s1b3, x1);
  fpsp_kernel<4096, 4, 1024, 1024, 0><<<dim3(2), dim3(1024), 0, stream>>>(q1, q2);
  knn_kernel<<<dim3(2048), dim3(256), 0, stream>>>(q1, q2, 1024, 4096, R2SQ, nbr2, cnt2);
  mlp2_kernel<<<dim3(2048), dim3(256), 0, stream>>>(q1, x1, q2, nbr2, cnt2,
                                                    s2W1, s2b1, s2W2, s2b2, s2W3, s2b3, x2);
  head_kernel<<<dim3(2048), dim3(256), 0, stream>>>(x2, l1W, l1b, l2W, l2b, l3W, l3b, out);

  // ---- ablation probes (R3 structure: 512 thr, PPT=16; identify by WG=512) ----
  // FLOOR: S=4096, recompute only at it=0  -> pure serial reduce/barrier chain.
  fpsp_kernel<8192, 16, 4096, 512, 1><<<dim3(2), dim3(512), 0, stream>>>(pos, qabl);
  // NOSKIP: S=2048 (halved; scale x2), recompute every iteration.
  fpsp_kernel<8192, 16, 2048, 512, 2><<<dim3(2), dim3(512), 0, stream>>>(pos, qabl);
}

// Round 5
// 7374.121 us; speedup vs baseline: 1.2562x; 1.2562x over previous
//
#include <hip/hip_runtime.h>
#include <math.h>

#define NEG_INF (-__builtin_inff())
#define POS_INF (__builtin_inff())

// ===================== DPP int max (valid f32 max for x >= 0) =====================
__device__ __forceinline__ int imax_i(int a, int b) { return a > b ? a : b; }

template<int CTRL, int RMASK>
__device__ __forceinline__ int dpp_imax_step(int y) {
  const int t = __builtin_amdgcn_update_dpp(y, y, CTRL, RMASK, 0xf, false);
  return imax_i(y, t);
}

// ============================ FPS (pruned, exact) ============================
// Bit-exact replica of reference lax.scan FPS:
//   q[it] = pts[last]; d = min(d, ||p - pts[last]||^2) (numpy op order, no FMA);
//   next = argmax(d) with first-ORIGINAL-index tie-break.
// Result-invariant acceleration:
//  - Morton-cell counting sort -> thread-chunks spatially compact; per-lane bbox
//    skip: mind2*0.99999 >= cval  =>  every nd >= every d in chunk => no change.
//  - CACHED WAVE-REDUCE: wave's reduced (max,argmin) only changes if one of its
//    lanes recomputed (ballot); clean waves skip the DPP chain entirely.
//  - block combine: one LDS u64 atomicMax per wave into a 4-rotating slot
//    (reset two-ahead by t0 before the barrier; validated R4).
//  - winner coords re-read from LDS; q_out written once at the end.
template<int N, int PPT, int S, int NT>
__global__ __launch_bounds__(NT) void fpsp_kernel(const float* __restrict__ pos,
                                                  float* __restrict__ q_out)
{
  constexpr int CELLS = 4096;      // 16^3 Morton cells
  constexpr int CPT = CELLS / NT;
  static_assert(N == NT * PPT, "chunking");
  static_assert(S <= CELLS, "winner list fits in hist");

  const int b = blockIdx.x;
  const int t = threadIdx.x;
  pos += (size_t)b * N * 3;
  q_out += (size_t)b * S * 3;

  __shared__ float sx[N], sy[N], sz[N];      // ORIGINAL-index order
  __shared__ int sorder[N];                  // slot -> orig
  __shared__ int hist[CELLS];                // reused as winner list after setup
  __shared__ int scanbuf[NT];
  __shared__ unsigned long long slot[4];     // rotating combine slots

  int* const swin = hist;                    // alias: setup-only vs loop-only

  // ---- load coords + cell histogram ----
  for (int i = t; i < CELLS; i += NT) hist[i] = 0;
  if (t < 4) slot[t] = 0;
  __syncthreads();
  for (int i = t; i < N; i += NT) {
    const float x = pos[3*i+0], y = pos[3*i+1], z = pos[3*i+2];
    sx[i] = x; sy[i] = y; sz[i] = z;
    int cx = (int)(x * 16.f); cx = cx < 0 ? 0 : (cx > 15 ? 15 : cx);
    int cy = (int)(y * 16.f); cy = cy < 0 ? 0 : (cy > 15 ? 15 : cy);
    int cz = (int)(z * 16.f); cz = cz < 0 ? 0 : (cz > 15 ? 15 : cz);
    int m = 0;
#pragma unroll
    for (int k = 0; k < 4; ++k)
      m |= (((cx >> k) & 1) << (3*k+2)) | (((cy >> k) & 1) << (3*k+1)) | (((cz >> k) & 1) << (3*k));
    atomicAdd(&hist[m], 1);
  }
  __syncthreads();
  // ---- exclusive scan of hist ----
  int loc[CPT]; int run = 0;
#pragma unroll
  for (int j = 0; j < CPT; ++j) { loc[j] = run; run += hist[t*CPT + j]; }
  scanbuf[t] = run;
  __syncthreads();
  for (int off = 1; off < NT; off <<= 1) {
    const int o = (t >= off) ? scanbuf[t - off] : 0;
    __syncthreads();
    scanbuf[t] += o;
    __syncthreads();
  }
  const int base = scanbuf[t] - run;   // exclusive block offset
#pragma unroll
  for (int j = 0; j < CPT; ++j) hist[t*CPT + j] = base + loc[j];
  __syncthreads();
  // ---- scatter (slot -> orig) ----
  for (int i = t; i < N; i += NT) {
    const float x = sx[i], y = sy[i], z = sz[i];
    int cx = (int)(x * 16.f); cx = cx < 0 ? 0 : (cx > 15 ? 15 : cx);
    int cy = (int)(y * 16.f); cy = cy < 0 ? 0 : (cy > 15 ? 15 : cy);
    int cz = (int)(z * 16.f); cz = cz < 0 ? 0 : (cz > 15 ? 15 : cz);
    int m = 0;
#pragma unroll
    for (int k = 0; k < 4; ++k)
      m |= (((cx >> k) & 1) << (3*k+2)) | (((cy >> k) & 1) << (3*k+1)) | (((cz >> k) & 1) << (3*k));
    const int sl = atomicAdd(&hist[m], 1);
    sorder[sl] = i;
  }
  __syncthreads();
  // ---- gather chunk into registers + bbox ----
  float px[PPT], py[PPT], pz[PPT], d[PPT];
  int og[PPT];
  float bxmin = POS_INF, bxmax = NEG_INF, bymin = POS_INF, bymax = NEG_INF,
        bzmin = POS_INF, bzmax = NEG_INF;
#pragma unroll
  for (int j = 0; j < PPT; ++j) {
    const int o = sorder[t*PPT + j];
    og[j] = o;
    const float x = sx[o], y = sy[o], z = sz[o];
    px[j] = x; py[j] = y; pz[j] = z;
    bxmin = fminf(bxmin, x); bxmax = fmaxf(bxmax, x);
    bymin = fminf(bymin, y); bymax = fmaxf(bymax, y);
    bzmin = fminf(bzmin, z); bzmax = fmaxf(bzmax, z);
    d[j] = POS_INF;
  }
  __syncthreads();   // hist fully consumed (sorder reads done) before swin reuse

  float cval = POS_INF;      // cached chunk max (inf -> force first recompute)
  int corig = 0x7fffffff;    // cached arg (orig idx)
  int wmvb = 0;              // cached wave-reduced max bits
  int wwo = 0x7fffffff;      // cached wave-reduced argmin-orig

  int worig = 0;             // first selected point = index 0
  int p = 0;

  for (int it = 0; it < S; ++it) {
    if (t == 0) swin[it] = worig;
    const float lx = sx[worig], ly = sy[worig], lz = sz[worig];

    // conservative bbox min dist^2 to (lx,ly,lz)
    const float ddx = fmaxf(0.f, fmaxf(bxmin - lx, lx - bxmax));
    const float ddy = fmaxf(0.f, fmaxf(bymin - ly, ly - bymax));
    const float ddz = fmaxf(0.f, fmaxf(bzmin - lz, lz - bzmax));
    const float mind2 = ddx*ddx + ddy*ddy + ddz*ddz;
    const bool rec = !(mind2 * 0.99999f >= cval);

    if (rec) {
      float bv = -1.f; int bo = 0x7fffffff;
#pragma unroll
      for (int j = 0; j < PPT; ++j) {
        const float dx = __fsub_rn(px[j], lx);
        const float dy = __fsub_rn(py[j], ly);
        const float dz = __fsub_rn(pz[j], lz);
        const float nd = __fadd_rn(__fadd_rn(__fmul_rn(dx, dx), __fmul_rn(dy, dy)),
                                   __fmul_rn(dz, dz));
        const float dn = __builtin_fminf(d[j], nd);
        d[j] = dn;
        if (dn > bv || (dn == bv && og[j] < bo)) { bv = dn; bo = og[j]; }
      }
      cval = bv; corig = bo;
    }

    // ---- wave reduce ONLY if some lane of this wave changed (dirty) ----
    if (__ballot(rec) != 0ULL) {
      const int x = __float_as_int(cval);
      int y = x;
      y = dpp_imax_step<0x111, 0xf>(y);  // row_shr:1
      y = dpp_imax_step<0x112, 0xf>(y);  // row_shr:2
      y = dpp_imax_step<0x114, 0xf>(y);  // row_shr:4
      y = dpp_imax_step<0x118, 0xf>(y);  // row_shr:8
      y = dpp_imax_step<0x142, 0xa>(y);  // row_bcast:15 -> rows 1,3
      y = dpp_imax_step<0x143, 0xc>(y);  // row_bcast:31 -> rows 2,3
      wmvb = __builtin_amdgcn_readlane(y, 63);
      unsigned long long tie = __ballot(__float_as_int(cval) == wmvb);
      int wo = 0x7fffffff;
      while (tie) {                      // usually a single iteration
        const int l = __builtin_ctzll(tie);
        const int o = __builtin_amdgcn_readlane(corig, l);
        wo = wo < o ? wo : o;
        tie &= tie - 1;
      }
      wwo = wo;
    }

    // one atomic per wave into the rotating combine slot
    if ((t & 63) == 0)
      atomicMax(&slot[p], ((unsigned long long)(unsigned)wmvb << 32) |
                          (unsigned)~(unsigned)wwo);
    if (t == 0) slot[(p + 1) & 3] = 0;   // reset distinct slot, pre-barrier safe
    __syncthreads();
    const unsigned long long wm = slot[p];
    worig = (int)(~(unsigned)(wm & 0xffffffffULL));
    p = (p + 1) & 3;
  }

  __syncthreads();   // swin[] complete before coalesced writeback
  for (int s = t; s < S; s += NT) {
    const int o = swin[s];
    q_out[3*s+0] = sx[o]; q_out[3*s+1] = sy[o]; q_out[3*s+2] = sz[o];
  }
}

// ============================ radius-KNN ============================
#define KNN_CAP 2048

__global__ __launch_bounds__(256) void knn_kernel(const float* __restrict__ cand,
                                                  const float* __restrict__ qpos,
                                                  int nq_per_graph, int n_cand, float r2,
                                                  int* __restrict__ nbr_out,
                                                  int* __restrict__ cnt_out)
{
  const int qi = blockIdx.x;
  const int t = threadIdx.x;
  const int b = qi / nq_per_graph;
  const float* cb = cand + (size_t)b * n_cand * 3;
  const float qx = qpos[3*qi+0], qy = qpos[3*qi+1], qz = qpos[3*qi+2];

  __shared__ unsigned long long keys[KNN_CAP];
  __shared__ int s_cnt;
  if (t == 0) s_cnt = 0;
  __syncthreads();

  for (int i = t; i < n_cand; i += 256) {
    const float dx = __fsub_rn(cb[3*i+0], qx);
    const float dy = __fsub_rn(cb[3*i+1], qy);
    const float dz = __fsub_rn(cb[3*i+2], qz);
    const float d2 = __fadd_rn(__fadd_rn(__fmul_rn(dx, dx), __fmul_rn(dy, dy)),
                               __fmul_rn(dz, dz));
    if (d2 <= r2) {
      const int p = atomicAdd(&s_cnt, 1);
      if (p < KNN_CAP) keys[p] = ((unsigned long long)__float_as_uint(d2) << 32) | (unsigned)i;
    }
  }
  __syncthreads();
  const int M = min(s_cnt, KNN_CAP);
  const int out_n = min(M, 64);
  if (M > 64) {
    int P = 128; while (P < M) P <<= 1;
    for (int i = M + t; i < P; i += 256) keys[i] = ~0ULL;
    __syncthreads();
    for (int k = 2; k <= P; k <<= 1) {
      for (int j = k >> 1; j > 0; j >>= 1) {
        for (int i = t; i < P; i += 256) {
          const int l = i ^ j;
          if (l > i) {
            const unsigned long long a = keys[i], c = keys[l];
            const bool up = ((i & k) == 0);
            if ((a > c) == up) { keys[i] = c; keys[l] = a; }
          }
        }
        __syncthreads();
      }
    }
  }
  if (t < 64) nbr_out[(size_t)qi*64 + t] = (t < out_n) ? (int)(keys[t] & 0xffffffffu) : -1;
  if (t == 0) cnt_out[qi] = out_n;
}

// ============================ SA1 edge MLP (3->64->64->128) + max ============================
__global__ __launch_bounds__(256) void mlp1_kernel(const float* __restrict__ pos,
                                                   const float* __restrict__ q1,
                                                   const int* __restrict__ nbr,
                                                   const int* __restrict__ cnt_,
                                                   const float* __restrict__ W1, const float* __restrict__ b1,
                                                   const float* __restrict__ W2, const float* __restrict__ b2,
                                                   const float* __restrict__ W3, const float* __restrict__ b3,
                                                   float* __restrict__ x1)
{
  const int qi = blockIdx.x;
  const int t = threadIdx.x;
  const int bg = qi >> 12;                       // 4096 queries per graph
  const float* cb = pos + (size_t)bg * 8192 * 3;

  __shared__ float sW1[3*64];
  __shared__ float sb1[64];
  __shared__ float sW2[64*64];
  __shared__ float sb2[64];
  __shared__ float sW3[64*128];
  __shared__ float sb3[128];
  __shared__ float featT[3][64];                 // k-major rel
  __shared__ float h1[64][65];
  __shared__ float h2b[64][65];

  const int cnt = cnt_[qi];
  const float qx = q1[3*qi+0], qy = q1[3*qi+1], qz = q1[3*qi+2];

  if (t < 64) {
    float r0 = 0.f, r1 = 0.f, r2v = 0.f;
    if (t < cnt) {
      const int nb = nbr[(size_t)qi*64 + t];
      r0 = cb[3*nb+0] - qx;
      r1 = cb[3*nb+1] - qy;
      r2v = cb[3*nb+2] - qz;
    }
    featT[0][t] = r0; featT[1][t] = r1; featT[2][t] = r2v;
  }
  for (int i = t; i < 192; i += 256) sW1[i] = W1[i];
  if (t < 64) { sb1[t] = b1[t]; sb2[t] = b2[t]; }
  for (int i = t; i < 4096; i += 256) sW2[i] = W2[i];
  for (int i = t; i < 8192; i += 256) sW3[i] = W3[i];
  if (t < 128) sb3[t] = b3[t];
  __syncthreads();

  const int e = t & 63, cg = t >> 6;
  { // layer1: 16 channels per thread
    const int c0 = cg * 16;
    const float a0 = featT[0][e], a1 = featT[1][e], a2 = featT[2][e];
#pragma unroll
    for (int i = 0; i < 16; ++i) {
      float v = sb1[c0+i];
      v = fmaf(a0, sW1[0*64 + c0+i], v);
      v = fmaf(a1, sW1[1*64 + c0+i], v);
      v = fmaf(a2, sW1[2*64 + c0+i], v);
      h1[e][c0+i] = fmaxf(v, 0.f);
    }
  }
  __syncthreads();
  { // layer2
    const int c0 = cg * 16;
    float acc[16];
#pragma unroll
    for (int i = 0; i < 16; ++i) acc[i] = sb2[c0+i];
    for (int k = 0; k < 64; ++k) {
      const float a = h1[e][k];
      const float4* wp = reinterpret_cast<const float4*>(&sW2[k*64 + c0]);
#pragma unroll
      for (int i = 0; i < 4; ++i) {
        const float4 w = wp[i];
        acc[4*i+0] = fmaf(a, w.x, acc[4*i+0]);
        acc[4*i+1] = fmaf(a, w.y, acc[4*i+1]);
        acc[4*i+2] = fmaf(a, w.z, acc[4*i+2]);
        acc[4*i+3] = fmaf(a, w.w, acc[4*i+3]);
      }
    }
#pragma unroll
    for (int i = 0; i < 16; ++i) h2b[e][c0+i] = fmaxf(acc[i], 0.f);
  }
  __syncthreads();
  float acc3[32];
  const int c0h = cg * 32;
  { // layer3 (no relu)
#pragma unroll
    for (int i = 0; i < 32; ++i) acc3[i] = sb3[c0h+i];
    for (int k = 0; k < 64; ++k) {
      const float a = h2b[e][k];
      const float4* wp = reinterpret_cast<const float4*>(&sW3[k*128 + c0h]);
#pragma unroll
      for (int i = 0; i < 8; ++i) {
        const float4 w = wp[i];
        acc3[4*i+0] = fmaf(a, w.x, acc3[4*i+0]);
        acc3[4*i+1] = fmaf(a, w.y, acc3[4*i+1]);
        acc3[4*i+2] = fmaf(a, w.z, acc3[4*i+2]);
        acc3[4*i+3] = fmaf(a, w.w, acc3[4*i+3]);
      }
    }
  }
  __syncthreads();       // all reads of h1/h2b done before re-staging
  {
    const bool valid = (e < cnt);
#pragma unroll
    for (int i = 0; i < 32; ++i) {
      const float v = valid ? acc3[i] : NEG_INF;
      const int c = c0h + i;
      if (c < 64) h1[e][c] = v; else h2b[e][c-64] = v;
    }
  }
  __syncthreads();
  if (t < 128) {
    float m = NEG_INF;
    if (t < 64) {
      for (int ee = 0; ee < 64; ++ee) m = fmaxf(m, h1[ee][t]);
    } else {
      for (int ee = 0; ee < 64; ++ee) m = fmaxf(m, h2b[ee][t-64]);
    }
    x1[(size_t)qi*128 + t] = m;
  }
}

// ============================ SA2 edge MLP (131->128->128->256) + max ============================
__global__ __launch_bounds__(256) void mlp2_kernel(const float* __restrict__ q1,
                                                   const float* __restrict__ x1,
                                                   const float* __restrict__ q2,
                                                   const int* __restrict__ nbr,
                                                   const int* __restrict__ cnt_,
                                                   const float* __restrict__ W1, const float* __restrict__ b1,
                                                   const float* __restrict__ W2, const float* __restrict__ b2,
                                                   const float* __restrict__ W3, const float* __restrict__ b3,
                                                   float* __restrict__ x2)
{
  const int qi = blockIdx.x;
  const int t = threadIdx.x;
  const int bg = qi >> 10;                       // 1024 queries per graph
  const float* cb = q1 + (size_t)bg * 4096 * 3;
  const float* xb = x1 + (size_t)bg * 4096 * 128;

  __shared__ float sW[131*128];                  // staged layer weights
  __shared__ float sb[256];
  __shared__ float featT[131][64];               // k-major feat; reused as h2
  __shared__ float hbuf[64][129];                // h1; reused as h3 stage
  __shared__ int snb[64];

  const int cnt = cnt_[qi];
  const float qx = q2[3*qi+0], qy = q2[3*qi+1], qz = q2[3*qi+2];

  if (t < 64) {
    const int nb = (t < cnt) ? nbr[(size_t)qi*64 + t] : 0;
    snb[t] = nb;
    float r0 = 0.f, r1 = 0.f, r2v = 0.f;
    if (t < cnt) {
      r0 = cb[3*nb+0] - qx;
      r1 = cb[3*nb+1] - qy;
      r2v = cb[3*nb+2] - qz;
    }
    featT[128][t] = r0; featT[129][t] = r1; featT[130][t] = r2v;
  }
  for (int i = t; i < 131*128; i += 256) sW[i] = W1[i];
  if (t < 128) sb[t] = b1[t];
  __syncthreads();
  for (int idx = t; idx < 64*128; idx += 256) {   // gather x1 features
    const int e = idx >> 7, k = idx & 127;
    featT[k][e] = (e < cnt) ? xb[(size_t)snb[e]*128 + k] : 0.f;
  }
  __syncthreads();

  const int e = t & 63, cg = t >> 6, c0 = cg * 32;
  float acc[32];
  { // layer1: 131 -> 128
#pragma unroll
    for (int i = 0; i < 32; ++i) acc[i] = sb[c0+i];
    for (int k = 0; k < 131; ++k) {
      const float a = featT[k][e];
      const float4* wp = reinterpret_cast<const float4*>(&sW[k*128 + c0]);
#pragma unroll
      for (int i = 0; i < 8; ++i) {
        const float4 w = wp[i];
        acc[4*i+0] = fmaf(a, w.x, acc[4*i+0]);
        acc[4*i+1] = fmaf(a, w.y, acc[4*i+1]);
        acc[4*i+2] = fmaf(a, w.z, acc[4*i+2]);
        acc[4*i+3] = fmaf(a, w.w, acc[4*i+3]);
      }
    }
#pragma unroll
    for (int i = 0; i < 32; ++i) hbuf[e][c0+i] = fmaxf(acc[i], 0.f);
  }
  __syncthreads();
  for (int i = t; i < 128*128; i += 256) sW[i] = W2[i];
  if (t < 128) sb[t] = b2[t];
  __syncthreads();
  { // layer2: 128 -> 128 ; h2 stored k-major into featT region
#pragma unroll
    for (int i = 0; i < 32; ++i) acc[i] = sb[c0+i];
    for (int k = 0; k < 128; ++k) {
      const float a = hbuf[e][k];
      const float4* wp = reinterpret_cast<const float4*>(&sW[k*128 + c0]);
#pragma unroll
      for (int i = 0; i < 8; ++i) {
        const float4 w = wp[i];
        acc[4*i+0] = fmaf(a, w.x, acc[4*i+0]);
        acc[4*i+1] = fmaf(a, w.y, acc[4*i+1]);
        acc[4*i+2] = fmaf(a, w.z, acc[4*i+2]);
        acc[4*i+3] = fmaf(a, w.w, acc[4*i+3]);
      }
    }
  }
  __syncthreads();   // everyone done reading hbuf(h1) and sW(W2)
#pragma unroll
  for (int i = 0; i < 32; ++i) featT[c0+i][e] = fmaxf(acc[i], 0.f);
  __syncthreads();
  // layer3: 128 -> 256, in two column halves (staged W3 halves), masked max
  for (int hh = 0; hh < 2; ++hh) {
    for (int i = t; i < 128*128; i += 256) {
      const int k = i >> 7, c = i & 127;
      sW[i] = W3[k*256 + hh*128 + c];
    }
    if (t < 128) sb[t] = b3[hh*128 + t];
    __syncthreads();
#pragma unroll
    for (int i = 0; i < 32; ++i) acc[i] = sb[c0+i];
    for (int k = 0; k < 128; ++k) {
      const float a = featT[k][e];
      const float4* wp = reinterpret_cast<const float4*>(&sW[k*128 + c0]);
#pragma unroll
      for (int i = 0; i < 8; ++i) {
        const float4 w = wp[i];
        acc[4*i+0] = fmaf(a, w.x, acc[4*i+0]);
        acc[4*i+1] = fmaf(a, w.y, acc[4*i+1]);
        acc[4*i+2] = fmaf(a, w.z, acc[4*i+2]);
        acc[4*i+3] = fmaf(a, w.w, acc[4*i+3]);
      }
    }
    const bool valid = (e < cnt);
#pragma unroll
    for (int i = 0; i < 32; ++i) hbuf[e][c0+i] = valid ? acc[i] : NEG_INF;
    __syncthreads();
    if (t < 128) {
      float m = NEG_INF;
      for (int ee = 0; ee < 64; ++ee) m = fmaxf(m, hbuf[ee][t]);
      x2[(size_t)qi*256 + hh*128 + t] = m;
    }
    __syncthreads();  // hbuf reads + sW reads done before next half
  }
}

// ============================ head MLP (256->256->128->1, sigmoid) ============================
__global__ __launch_bounds__(256) void head_kernel(const float* __restrict__ x2,
                                                   const float* __restrict__ W1, const float* __restrict__ b1,
                                                   const float* __restrict__ W2, const float* __restrict__ b2,
                                                   const float* __restrict__ W3, const float* __restrict__ b3,
                                                   float* __restrict__ out)
{
  const int pt = blockIdx.x;
  const int t = threadIdx.x;
  __shared__ float sx[256];
  __shared__ float sh1[256];
  __shared__ float sh2[128];
  __shared__ float red[128];

  sx[t] = x2[(size_t)pt*256 + t];
  __syncthreads();
  float a1 = b1[t];
  for (int k = 0; k < 256; ++k) a1 = fmaf(sx[k], W1[k*256 + t], a1);
  sh1[t] = fmaxf(a1, 0.f);
  __syncthreads();
  if (t < 128) {
    float a2 = b2[t];
    for (int k = 0; k < 256; ++k) a2 = fmaf(sh1[k], W2[k*128 + t], a2);
    sh2[t] = fmaxf(a2, 0.f);
  }
  __syncthreads();
  if (t < 128) red[t] = sh2[t] * W3[t];
  __syncthreads();
  for (int o = 64; o > 0; o >>= 1) {
    if (t < o) red[t] += red[t + o];
    __syncthreads();
  }
  if (t == 0) {
    const float v = red[0] + b3[0];
    out[pt] = 1.f / (1.f + expf(-v));
  }
}

// ============================ launcher ============================
extern "C" void kernel_launch(void* const* d_in, const int* in_sizes, int n_in,
                              void* d_out, int out_size, void* d_ws, size_t ws_size,
                              hipStream_t stream)
{
  (void)in_sizes; (void)n_in; (void)out_size; (void)ws_size;
  const float* pos  = (const float*)d_in[0];
  // d_in[1] = batch (sorted, equal graphs) — layout implied, unused
  const float* s1W1 = (const float*)d_in[2];  const float* s1b1 = (const float*)d_in[3];
  const float* s1W2 = (const float*)d_in[4];  const float* s1b2 = (const float*)d_in[5];
  const float* s1W3 = (const float*)d_in[6];  const float* s1b3 = (const float*)d_in[7];
  const float* s2W1 = (const float*)d_in[8];  const float* s2b1 = (const float*)d_in[9];
  const float* s2W2 = (const float*)d_in[10]; const float* s2b2 = (const float*)d_in[11];
  const float* s2W3 = (const float*)d_in[12]; const float* s2b3 = (const float*)d_in[13];
  const float* l1W  = (const float*)d_in[14]; const float* l1b  = (const float*)d_in[15];
  const float* l2W  = (const float*)d_in[16]; const float* l2b  = (const float*)d_in[17];
  const float* l3W  = (const float*)d_in[18]; const float* l3b  = (const float*)d_in[19];
  float* out = (float*)d_out;

  char* w = (char*)d_ws;
  size_t off = 0;
  auto alloc = [&](size_t bytes) -> void* {
    void* p = w + off;
    off += (bytes + 255) & ~(size_t)255;
    return p;
  };
  float* q1   = (float*)alloc((size_t)2*4096*3*4);
  float* q2   = (float*)alloc((size_t)2*1024*3*4);
  float* x1   = (float*)alloc((size_t)8192*128*4);
  float* x2   = (float*)alloc((size_t)2048*256*4);
  int*   nbr1 = (int*)alloc((size_t)8192*64*4);
  int*   cnt1 = (int*)alloc((size_t)8192*4);
  int*   nbr2 = (int*)alloc((size_t)2048*64*4);
  int*   cnt2 = (int*)alloc((size_t)2048*4);

  const float R1SQ = (float)(0.2 * 0.2);   // mirrors Python double math -> f32
  const float R2SQ = (float)(0.4 * 0.4);

  fpsp_kernel<8192, 16, 4096, 512><<<dim3(2), dim3(512), 0, stream>>>(pos, q1);
  knn_kernel<<<dim3(8192), dim3(256), 0, stream>>>(pos, q1, 4096, 8192, R1SQ, nbr1, cnt1);
  mlp1_kernel<<<dim3(8192), dim3(256), 0, stream>>>(pos, q1, nbr1, cnt1,
                                                    s1W1, s1b1, s1W2, s1b2, s1W3, s1b3, x1);
  fpsp_kernel<4096, 8, 1024, 512><<<dim3(2), dim3(512), 0, stream>>>(q1, q2);
  knn_kernel<<<dim3(2048), dim3(256), 0, stream>>>(q1, q2, 1024, 4096, R2SQ, nbr2, cnt2);
  mlp2_kernel<<<dim3(2048), dim3(256), 0, stream>>>(q1, x1, q2, nbr2, cnt2,
                                                    s2W1, s2b1, s2W2, s2b2, s2W3, s2b3, x2);
  head_kernel<<<dim3(2048), dim3(256), 0, stream>>>(x2, l1W, l1b, l2W, l2b, l3W, l3b, out);
}

// Round 6
// 5163.153 us; speedup vs baseline: 1.7942x; 1.4282x over previous
//
#include <hip/hip_runtime.h>
#include <math.h>

#define NEG_INF (-__builtin_inff())
#define POS_INF (__builtin_inff())

// ===================== DPP int max (valid f32 max for x >= 0) =====================
__device__ __forceinline__ int imax_i(int a, int b) { return a > b ? a : b; }

template<int CTRL, int RMASK>
__device__ __forceinline__ int dpp_imax_step(int y) {
  const int t = __builtin_amdgcn_update_dpp(y, y, CTRL, RMASK, 0xf, false);
  return imax_i(y, t);
}

// ============================ FPS (pruned, exact) ============================
// Bit-exact replica of reference lax.scan FPS:
//   q[it] = pts[last]; d = min(d, ||p - pts[last]||^2) (numpy op order, no FMA);
//   next = argmax(d) with first-ORIGINAL-index tie-break.
// Result-invariant acceleration (measured across R2-R5):
//  - Morton-cell counting sort -> thread-chunks spatially compact; per-lane bbox
//    skip (mind2*0.99999 >= cval => no element of d can change).
//  - SMALL PPT IS KING (R4 vs R3/R5): per-iteration critical path = dirty-wave
//    recompute ~ PPT; 1024 thr / PPT=8 measured 3456us vs 512 thr / PPT=16
//    5712-5744us. Run at NT=1024.
//  - CACHED WAVE-REDUCE (R5): DPP chain + tie-ballot only when a lane of this
//    wave recomputed; clean waves reuse cached (wmvb,wwo). Halved VALUBusy.
//  - block combine: one LDS u64 atomicMax per wave into 4-rotating slots
//    (t0 resets the next slot pre-barrier; validated R4/R5).
//  - winner coords re-read from LDS; q_out written once at the end (R3).
template<int N, int PPT, int S, int NT>
__global__ __launch_bounds__(NT) void fpsp_kernel(const float* __restrict__ pos,
                                                  float* __restrict__ q_out)
{
  constexpr int CELLS = 4096;      // 16^3 Morton cells
  constexpr int CPT = CELLS / NT;
  static_assert(N == NT * PPT, "chunking");
  static_assert(S <= CELLS, "winner list fits in hist");

  const int b = blockIdx.x;
  const int t = threadIdx.x;
  pos += (size_t)b * N * 3;
  q_out += (size_t)b * S * 3;

  __shared__ float sx[N], sy[N], sz[N];      // ORIGINAL-index order
  __shared__ int sorder[N];                  // slot -> orig
  __shared__ int hist[CELLS];                // reused as winner list after setup
  __shared__ int scanbuf[NT];
  __shared__ unsigned long long slot[4];     // rotating combine slots

  int* const swin = hist;                    // alias: setup-only vs loop-only

  // ---- load coords + cell histogram ----
  for (int i = t; i < CELLS; i += NT) hist[i] = 0;
  if (t < 4) slot[t] = 0;
  __syncthreads();
  for (int i = t; i < N; i += NT) {
    const float x = pos[3*i+0], y = pos[3*i+1], z = pos[3*i+2];
    sx[i] = x; sy[i] = y; sz[i] = z;
    int cx = (int)(x * 16.f); cx = cx < 0 ? 0 : (cx > 15 ? 15 : cx);
    int cy = (int)(y * 16.f); cy = cy < 0 ? 0 : (cy > 15 ? 15 : cy);
    int cz = (int)(z * 16.f); cz = cz < 0 ? 0 : (cz > 15 ? 15 : cz);
    int m = 0;
#pragma unroll
    for (int k = 0; k < 4; ++k)
      m |= (((cx >> k) & 1) << (3*k+2)) | (((cy >> k) & 1) << (3*k+1)) | (((cz >> k) & 1) << (3*k));
    atomicAdd(&hist[m], 1);
  }
  __syncthreads();
  // ---- exclusive scan of hist ----
  int loc[CPT]; int run = 0;
#pragma unroll
  for (int j = 0; j < CPT; ++j) { loc[j] = run; run += hist[t*CPT + j]; }
  scanbuf[t] = run;
  __syncthreads();
  for (int off = 1; off < NT; off <<= 1) {
    const int o = (t >= off) ? scanbuf[t - off] : 0;
    __syncthreads();
    scanbuf[t] += o;
    __syncthreads();
  }
  const int base = scanbuf[t] - run;   // exclusive block offset
#pragma unroll
  for (int j = 0; j < CPT; ++j) hist[t*CPT + j] = base + loc[j];
  __syncthreads();
  // ---- scatter (slot -> orig) ----
  for (int i = t; i < N; i += NT) {
    const float x = sx[i], y = sy[i], z = sz[i];
    int cx = (int)(x * 16.f); cx = cx < 0 ? 0 : (cx > 15 ? 15 : cx);
    int cy = (int)(y * 16.f); cy = cy < 0 ? 0 : (cy > 15 ? 15 : cy);
    int cz = (int)(z * 16.f); cz = cz < 0 ? 0 : (cz > 15 ? 15 : cz);
    int m = 0;
#pragma unroll
    for (int k = 0; k < 4; ++k)
      m |= (((cx >> k) & 1) << (3*k+2)) | (((cy >> k) & 1) << (3*k+1)) | (((cz >> k) & 1) << (3*k));
    const int sl = atomicAdd(&hist[m], 1);
    sorder[sl] = i;
  }
  __syncthreads();
  // ---- gather chunk into registers + bbox ----
  float px[PPT], py[PPT], pz[PPT], d[PPT];
  int og[PPT];
  float bxmin = POS_INF, bxmax = NEG_INF, bymin = POS_INF, bymax = NEG_INF,
        bzmin = POS_INF, bzmax = NEG_INF;
#pragma unroll
  for (int j = 0; j < PPT; ++j) {
    const int o = sorder[t*PPT + j];
    og[j] = o;
    const float x = sx[o], y = sy[o], z = sz[o];
    px[j] = x; py[j] = y; pz[j] = z;
    bxmin = fminf(bxmin, x); bxmax = fmaxf(bxmax, x);
    bymin = fminf(bymin, y); bymax = fmaxf(bymax, y);
    bzmin = fminf(bzmin, z); bzmax = fmaxf(bzmax, z);
    d[j] = POS_INF;
  }
  __syncthreads();   // hist fully consumed (sorder reads done) before swin reuse

  float cval = POS_INF;      // cached chunk max (inf -> force first recompute)
  int corig = 0x7fffffff;    // cached arg (orig idx)
  int wmvb = 0;              // cached wave-reduced max bits
  int wwo = 0x7fffffff;      // cached wave-reduced argmin-orig

  int worig = 0;             // first selected point = index 0
  int p = 0;

  for (int it = 0; it < S; ++it) {
    if (t == 0) swin[it] = worig;
    const float lx = sx[worig], ly = sy[worig], lz = sz[worig];

    // conservative bbox min dist^2 to (lx,ly,lz)
    const float ddx = fmaxf(0.f, fmaxf(bxmin - lx, lx - bxmax));
    const float ddy = fmaxf(0.f, fmaxf(bymin - ly, ly - bymax));
    const float ddz = fmaxf(0.f, fmaxf(bzmin - lz, lz - bzmax));
    const float mind2 = ddx*ddx + ddy*ddy + ddz*ddz;
    const bool rec = !(mind2 * 0.99999f >= cval);

    if (rec) {
      float bv = -1.f; int bo = 0x7fffffff;
#pragma unroll
      for (int j = 0; j < PPT; ++j) {
        const float dx = __fsub_rn(px[j], lx);
        const float dy = __fsub_rn(py[j], ly);
        const float dz = __fsub_rn(pz[j], lz);
        const float nd = __fadd_rn(__fadd_rn(__fmul_rn(dx, dx), __fmul_rn(dy, dy)),
                                   __fmul_rn(dz, dz));
        const float dn = __builtin_fminf(d[j], nd);
        d[j] = dn;
        if (dn > bv || (dn == bv && og[j] < bo)) { bv = dn; bo = og[j]; }
      }
      cval = bv; corig = bo;
    }

    // ---- wave reduce ONLY if some lane of this wave changed (dirty) ----
    if (__ballot(rec) != 0ULL) {
      const int x = __float_as_int(cval);
      int y = x;
      y = dpp_imax_step<0x111, 0xf>(y);  // row_shr:1
      y = dpp_imax_step<0x112, 0xf>(y);  // row_shr:2
      y = dpp_imax_step<0x114, 0xf>(y);  // row_shr:4
      y = dpp_imax_step<0x118, 0xf>(y);  // row_shr:8
      y = dpp_imax_step<0x142, 0xa>(y);  // row_bcast:15 -> rows 1,3
      y = dpp_imax_step<0x143, 0xc>(y);  // row_bcast:31 -> rows 2,3
      wmvb = __builtin_amdgcn_readlane(y, 63);
      unsigned long long tie = __ballot(__float_as_int(cval) == wmvb);
      int wo = 0x7fffffff;
      while (tie) {                      // usually a single iteration
        const int l = __builtin_ctzll(tie);
        const int o = __builtin_amdgcn_readlane(corig, l);
        wo = wo < o ? wo : o;
        tie &= tie - 1;
      }
      wwo = wo;
    }

    // one atomic per wave into the rotating combine slot
    if ((t & 63) == 0)
      atomicMax(&slot[p], ((unsigned long long)(unsigned)wmvb << 32) |
                          (unsigned)~(unsigned)wwo);
    if (t == 0) slot[(p + 1) & 3] = 0;   // reset distinct slot, pre-barrier safe
    __syncthreads();
    const unsigned long long wm = slot[p];
    worig = (int)(~(unsigned)(wm & 0xffffffffULL));
    p = (p + 1) & 3;
  }

  __syncthreads();   // swin[] complete before coalesced writeback
  for (int s = t; s < S; s += NT) {
    const int o = swin[s];
    q_out[3*s+0] = sx[o]; q_out[3*s+1] = sy[o]; q_out[3*s+2] = sz[o];
  }
}

// ============================ radius-KNN ============================
#define KNN_CAP 2048

__global__ __launch_bounds__(256) void knn_kernel(const float* __restrict__ cand,
                                                  const float* __restrict__ qpos,
                                                  int nq_per_graph, int n_cand, float r2,
                                                  int* __restrict__ nbr_out,
                                                  int* __restrict__ cnt_out)
{
  const int qi = blockIdx.x;
  const int t = threadIdx.x;
  const int b = qi / nq_per_graph;
  const float* cb = cand + (size_t)b * n_cand * 3;
  const float qx = qpos[3*qi+0], qy = qpos[3*qi+1], qz = qpos[3*qi+2];

  __shared__ unsigned long long keys[KNN_CAP];
  __shared__ int s_cnt;
  if (t == 0) s_cnt = 0;
  __syncthreads();

  for (int i = t; i < n_cand; i += 256) {
    const float dx = __fsub_rn(cb[3*i+0], qx);
    const float dy = __fsub_rn(cb[3*i+1], qy);
    const float dz = __fsub_rn(cb[3*i+2], qz);
    const float d2 = __fadd_rn(__fadd_rn(__fmul_rn(dx, dx), __fmul_rn(dy, dy)),
                               __fmul_rn(dz, dz));
    if (d2 <= r2) {
      const int p = atomicAdd(&s_cnt, 1);
      if (p < KNN_CAP) keys[p] = ((unsigned long long)__float_as_uint(d2) << 32) | (unsigned)i;
    }
  }
  __syncthreads();
  const int M = min(s_cnt, KNN_CAP);
  const int out_n = min(M, 64);
  if (M > 64) {
    int P = 128; while (P < M) P <<= 1;
    for (int i = M + t; i < P; i += 256) keys[i] = ~0ULL;
    __syncthreads();
    for (int k = 2; k <= P; k <<= 1) {
      for (int j = k >> 1; j > 0; j >>= 1) {
        for (int i = t; i < P; i += 256) {
          const int l = i ^ j;
          if (l > i) {
            const unsigned long long a = keys[i], c = keys[l];
            const bool up = ((i & k) == 0);
            if ((a > c) == up) { keys[i] = c; keys[l] = a; }
          }
        }
        __syncthreads();
      }
    }
  }
  if (t < 64) nbr_out[(size_t)qi*64 + t] = (t < out_n) ? (int)(keys[t] & 0xffffffffu) : -1;
  if (t == 0) cnt_out[qi] = out_n;
}

// ============================ SA1 edge MLP (3->64->64->128) + max ============================
__global__ __launch_bounds__(256) void mlp1_kernel(const float* __restrict__ pos,
                                                   const float* __restrict__ q1,
                                                   const int* __restrict__ nbr,
                                                   const int* __restrict__ cnt_,
                                                   const float* __restrict__ W1, const float* __restrict__ b1,
                                                   const float* __restrict__ W2, const float* __restrict__ b2,
                                                   const float* __restrict__ W3, const float* __restrict__ b3,
                                                   float* __restrict__ x1)
{
  const int qi = blockIdx.x;
  const int t = threadIdx.x;
  const int bg = qi >> 12;                       // 4096 queries per graph
  const float* cb = pos + (size_t)bg * 8192 * 3;

  __shared__ float sW1[3*64];
  __shared__ float sb1[64];
  __shared__ float sW2[64*64];
  __shared__ float sb2[64];
  __shared__ float sW3[64*128];
  __shared__ float sb3[128];
  __shared__ float featT[3][64];                 // k-major rel
  __shared__ float h1[64][65];
  __shared__ float h2b[64][65];

  const int cnt = cnt_[qi];
  const float qx = q1[3*qi+0], qy = q1[3*qi+1], qz = q1[3*qi+2];

  if (t < 64) {
    float r0 = 0.f, r1 = 0.f, r2v = 0.f;
    if (t < cnt) {
      const int nb = nbr[(size_t)qi*64 + t];
      r0 = cb[3*nb+0] - qx;
      r1 = cb[3*nb+1] - qy;
      r2v = cb[3*nb+2] - qz;
    }
    featT[0][t] = r0; featT[1][t] = r1; featT[2][t] = r2v;
  }
  for (int i = t; i < 192; i += 256) sW1[i] = W1[i];
  if (t < 64) { sb1[t] = b1[t]; sb2[t] = b2[t]; }
  for (int i = t; i < 4096; i += 256) sW2[i] = W2[i];
  for (int i = t; i < 8192; i += 256) sW3[i] = W3[i];
  if (t < 128) sb3[t] = b3[t];
  __syncthreads();

  const int e = t & 63, cg = t >> 6;
  { // layer1: 16 channels per thread
    const int c0 = cg * 16;
    const float a0 = featT[0][e], a1 = featT[1][e], a2 = featT[2][e];
#pragma unroll
    for (int i = 0; i < 16; ++i) {
      float v = sb1[c0+i];
      v = fmaf(a0, sW1[0*64 + c0+i], v);
      v = fmaf(a1, sW1[1*64 + c0+i], v);
      v = fmaf(a2, sW1[2*64 + c0+i], v);
      h1[e][c0+i] = fmaxf(v, 0.f);
    }
  }
  __syncthreads();
  { // layer2
    const int c0 = cg * 16;
    float acc[16];
#pragma unroll
    for (int i = 0; i < 16; ++i) acc[i] = sb2[c0+i];
    for (int k = 0; k < 64; ++k) {
      const float a = h1[e][k];
      const float4* wp = reinterpret_cast<const float4*>(&sW2[k*64 + c0]);
#pragma unroll
      for (int i = 0; i < 4; ++i) {
        const float4 w = wp[i];
        acc[4*i+0] = fmaf(a, w.x, acc[4*i+0]);
        acc[4*i+1] = fmaf(a, w.y, acc[4*i+1]);
        acc[4*i+2] = fmaf(a, w.z, acc[4*i+2]);
        acc[4*i+3] = fmaf(a, w.w, acc[4*i+3]);
      }
    }
#pragma unroll
    for (int i = 0; i < 16; ++i) h2b[e][c0+i] = fmaxf(acc[i], 0.f);
  }
  __syncthreads();
  float acc3[32];
  const int c0h = cg * 32;
  { // layer3 (no relu)
#pragma unroll
    for (int i = 0; i < 32; ++i) acc3[i] = sb3[c0h+i];
    for (int k = 0; k < 64; ++k) {
      const float a = h2b[e][k];
      const float4* wp = reinterpret_cast<const float4*>(&sW3[k*128 + c0h]);
#pragma unroll
      for (int i = 0; i < 8; ++i) {
        const float4 w = wp[i];
        acc3[4*i+0] = fmaf(a, w.x, acc3[4*i+0]);
        acc3[4*i+1] = fmaf(a, w.y, acc3[4*i+1]);
        acc3[4*i+2] = fmaf(a, w.z, acc3[4*i+2]);
        acc3[4*i+3] = fmaf(a, w.w, acc3[4*i+3]);
      }
    }
  }
  __syncthreads();       // all reads of h1/h2b done before re-staging
  {
    const bool valid = (e < cnt);
#pragma unroll
    for (int i = 0; i < 32; ++i) {
      const float v = valid ? acc3[i] : NEG_INF;
      const int c = c0h + i;
      if (c < 64) h1[e][c] = v; else h2b[e][c-64] = v;
    }
  }
  __syncthreads();
  if (t < 128) {
    float m = NEG_INF;
    if (t < 64) {
      for (int ee = 0; ee < 64; ++ee) m = fmaxf(m, h1[ee][t]);
    } else {
      for (int ee = 0; ee < 64; ++ee) m = fmaxf(m, h2b[ee][t-64]);
    }
    x1[(size_t)qi*128 + t] = m;
  }
}

// ============================ SA2 edge MLP (131->128->128->256) + max ============================
__global__ __launch_bounds__(256) void mlp2_kernel(const float* __restrict__ q1,
                                                   const float* __restrict__ x1,
                                                   const float* __restrict__ q2,
                                                   const int* __restrict__ nbr,
                                                   const int* __restrict__ cnt_,
                                                   const float* __restrict__ W1, const float* __restrict__ b1,
                                                   const float* __restrict__ W2, const float* __restrict__ b2,
                                                   const float* __restrict__ W3, const float* __restrict__ b3,
                                                   float* __restrict__ x2)
{
  const int qi = blockIdx.x;
  const int t = threadIdx.x;
  const int bg = qi >> 10;                       // 1024 queries per graph
  const float* cb = q1 + (size_t)bg * 4096 * 3;
  const float* xb = x1 + (size_t)bg * 4096 * 128;

  __shared__ float sW[131*128];                  // staged layer weights
  __shared__ float sb[256];
  __shared__ float featT[131][64];               // k-major feat; reused as h2
  __shared__ float hbuf[64][129];                // h1; reused as h3 stage
  __shared__ int snb[64];

  const int cnt = cnt_[qi];
  const float qx = q2[3*qi+0], qy = q2[3*qi+1], qz = q2[3*qi+2];

  if (t < 64) {
    const int nb = (t < cnt) ? nbr[(size_t)qi*64 + t] : 0;
    snb[t] = nb;
    float r0 = 0.f, r1 = 0.f, r2v = 0.f;
    if (t < cnt) {
      r0 = cb[3*nb+0] - qx;
      r1 = cb[3*nb+1] - qy;
      r2v = cb[3*nb+2] - qz;
    }
    featT[128][t] = r0; featT[129][t] = r1; featT[130][t] = r2v;
  }
  for (int i = t; i < 131*128; i += 256) sW[i] = W1[i];
  if (t < 128) sb[t] = b1[t];
  __syncthreads();
  for (int idx = t; idx < 64*128; idx += 256) {   // gather x1 features
    const int e = idx >> 7, k = idx & 127;
    featT[k][e] = (e < cnt) ? xb[(size_t)snb[e]*128 + k] : 0.f;
  }
  __syncthreads();

  const int e = t & 63, cg = t >> 6, c0 = cg * 32;
  float acc[32];
  { // layer1: 131 -> 128
#pragma unroll
    for (int i = 0; i < 32; ++i) acc[i] = sb[c0+i];
    for (int k = 0; k < 131; ++k) {
      const float a = featT[k][e];
      const float4* wp = reinterpret_cast<const float4*>(&sW[k*128 + c0]);
#pragma unroll
      for (int i = 0; i < 8; ++i) {
        const float4 w = wp[i];
        acc[4*i+0] = fmaf(a, w.x, acc[4*i+0]);
        acc[4*i+1] = fmaf(a, w.y, acc[4*i+1]);
        acc[4*i+2] = fmaf(a, w.z, acc[4*i+2]);
        acc[4*i+3] = fmaf(a, w.w, acc[4*i+3]);
      }
    }
#pragma unroll
    for (int i = 0; i < 32; ++i) hbuf[e][c0+i] = fmaxf(acc[i], 0.f);
  }
  __syncthreads();
  for (int i = t; i < 128*128; i += 256) sW[i] = W2[i];
  if (t < 128) sb[t] = b2[t];
  __syncthreads();
  { // layer2: 128 -> 128 ; h2 stored k-major into featT region
#pragma unroll
    for (int i = 0; i < 32; ++i) acc[i] = sb[c0+i];
    for (int k = 0; k < 128; ++k) {
      const float a = hbuf[e][k];
      const float4* wp = reinterpret_cast<const float4*>(&sW[k*128 + c0]);
#pragma unroll
      for (int i = 0; i < 8; ++i) {
        const float4 w = wp[i];
        acc[4*i+0] = fmaf(a, w.x, acc[4*i+0]);
        acc[4*i+1] = fmaf(a, w.y, acc[4*i+1]);
        acc[4*i+2] = fmaf(a, w.z, acc[4*i+2]);
        acc[4*i+3] = fmaf(a, w.w, acc[4*i+3]);
      }
    }
  }
  __syncthreads();   // everyone done reading hbuf(h1) and sW(W2)
#pragma unroll
  for (int i = 0; i < 32; ++i) featT[c0+i][e] = fmaxf(acc[i], 0.f);
  __syncthreads();
  // layer3: 128 -> 256, in two column halves (staged W3 halves), masked max
  for (int hh = 0; hh < 2; ++hh) {
    for (int i = t; i < 128*128; i += 256) {
      const int k = i >> 7, c = i & 127;
      sW[i] = W3[k*256 + hh*128 + c];
    }
    if (t < 128) sb[t] = b3[hh*128 + t];
    __syncthreads();
#pragma unroll
    for (int i = 0; i < 32; ++i) acc[i] = sb[c0+i];
    for (int k = 0; k < 128; ++k) {
      const float a = featT[k][e];
      const float4* wp = reinterpret_cast<const float4*>(&sW[k*128 + c0]);
#pragma unroll
      for (int i = 0; i < 8; ++i) {
        const float4 w = wp[i];
        acc[4*i+0] = fmaf(a, w.x, acc[4*i+0]);
        acc[4*i+1] = fmaf(a, w.y, acc[4*i+1]);
        acc[4*i+2] = fmaf(a, w.z, acc[4*i+2]);
        acc[4*i+3] = fmaf(a, w.w, acc[4*i+3]);
      }
    }
    const bool valid = (e < cnt);
#pragma unroll
    for (int i = 0; i < 32; ++i) hbuf[e][c0+i] = valid ? acc[i] : NEG_INF;
    __syncthreads();
    if (t < 128) {
      float m = NEG_INF;
      for (int ee = 0; ee < 64; ++ee) m = fmaxf(m, hbuf[ee][t]);
      x2[(size_t)qi*256 + hh*128 + t] = m;
    }
    __syncthreads();  // hbuf reads + sW reads done before next half
  }
}

// ============================ head MLP (256->256->128->1, sigmoid) ============================
__global__ __launch_bounds__(256) void head_kernel(const float* __restrict__ x2,
                                                   const float* __restrict__ W1, const float* __restrict__ b1,
                                                   const float* __restrict__ W2, const float* __restrict__ b2,
                                                   const float* __restrict__ W3, const float* __restrict__ b3,
                                                   float* __restrict__ out)
{
  const int pt = blockIdx.x;
  const int t = threadIdx.x;
  __shared__ float sx[256];
  __shared__ float sh1[256];
  __shared__ float sh2[128];
  __shared__ float red[128];

  sx[t] = x2[(size_t)pt*256 + t];
  __syncthreads();
  float a1 = b1[t];
  for (int k = 0; k < 256; ++k) a1 = fmaf(sx[k], W1[k*256 + t], a1);
  sh1[t] = fmaxf(a1, 0.f);
  __syncthreads();
  if (t < 128) {
    float a2 = b2[t];
    for (int k = 0; k < 256; ++k) a2 = fmaf(sh1[k], W2[k*128 + t], a2);
    sh2[t] = fmaxf(a2, 0.f);
  }
  __syncthreads();
  if (t < 128) red[t] = sh2[t] * W3[t];
  __syncthreads();
  for (int o = 64; o > 0; o >>= 1) {
    if (t < o) red[t] += red[t + o];
    __syncthreads();
  }
  if (t == 0) {
    const float v = red[0] + b3[0];
    out[pt] = 1.f / (1.f + expf(-v));
  }
}

// ============================ launcher ============================
extern "C" void kernel_launch(void* const* d_in, const int* in_sizes, int n_in,
                              void* d_out, int out_size, void* d_ws, size_t ws_size,
                              hipStream_t stream)
{
  (void)in_sizes; (void)n_in; (void)out_size; (void)ws_size;
  const float* pos  = (const float*)d_in[0];
  // d_in[1] = batch (sorted, equal graphs) — layout implied, unused
  const float* s1W1 = (const float*)d_in[2];  const float* s1b1 = (const float*)d_in[3];
  const float* s1W2 = (const float*)d_in[4];  const float* s1b2 = (const float*)d_in[5];
  const float* s1W3 = (const float*)d_in[6];  const float* s1b3 = (const float*)d_in[7];
  const float* s2W1 = (const float*)d_in[8];  const float* s2b1 = (const float*)d_in[9];
  const float* s2W2 = (const float*)d_in[10]; const float* s2b2 = (const float*)d_in[11];
  const float* s2W3 = (const float*)d_in[12]; const float* s2b3 = (const float*)d_in[13];
  const float* l1W  = (const float*)d_in[14]; const float* l1b  = (const float*)d_in[15];
  const float* l2W  = (const float*)d_in[16]; const float* l2b  = (const float*)d_in[17];
  const float* l3W  = (const float*)d_in[18]; const float* l3b  = (const float*)d_in[19];
  float* out = (float*)d_out;

  char* w = (char*)d_ws;
  size_t off = 0;
  auto alloc = [&](size_t bytes) -> void* {
    void* p = w + off;
    off += (bytes + 255) & ~(size_t)255;
    return p;
  };
  float* q1   = (float*)alloc((size_t)2*4096*3*4);
  float* q2   = (float*)alloc((size_t)2*1024*3*4);
  float* x1   = (float*)alloc((size_t)8192*128*4);
  float* x2   = (float*)alloc((size_t)2048*256*4);
  int*   nbr1 = (int*)alloc((size_t)8192*64*4);
  int*   cnt1 = (int*)alloc((size_t)8192*4);
  int*   nbr2 = (int*)alloc((size_t)2048*64*4);
  int*   cnt2 = (int*)alloc((size_t)2048*4);

  const float R1SQ = (float)(0.2 * 0.2);   // mirrors Python double math -> f32
  const float R2SQ = (float)(0.4 * 0.4);

  fpsp_kernel<8192, 8, 4096, 1024><<<dim3(2), dim3(1024), 0, stream>>>(pos, q1);
  knn_kernel<<<dim3(8192), dim3(256), 0, stream>>>(pos, q1, 4096, 8192, R1SQ, nbr1, cnt1);
  mlp1_kernel<<<dim3(8192), dim3(256), 0, stream>>>(pos, q1, nbr1, cnt1,
                                                    s1W1, s1b1, s1W2, s1b2, s1W3, s1b3, x1);
  fpsp_kernel<4096, 4, 1024, 1024><<<dim3(2), dim3(1024), 0, stream>>>(q1, q2);
  knn_kernel<<<dim3(2048), dim3(256), 0, stream>>>(q1, q2, 1024, 4096, R2SQ, nbr2, cnt2);
  mlp2_kernel<<<dim3(2048), dim3(256), 0, stream>>>(q1, x1, q2, nbr2, cnt2,
                                                    s2W1, s2b1, s2W2, s2b2, s2W3, s2b3, x2);
  head_kernel<<<dim3(2048), dim3(256), 0, stream>>>(x2, l1W, l1b, l2W, l2b, l3W, l3b, out);
}